// Round 9
// baseline (217.170 us; speedup 1.0000x reference)
//
#include <hip/hip_runtime.h>
#include <hip/hip_bf16.h>

typedef __bf16 bf16_t;
typedef __bf16 bf16x8 __attribute__((ext_vector_type(8)));
typedef float f32x4 __attribute__((ext_vector_type(4)));
typedef float f32x16 __attribute__((ext_vector_type(16)));
typedef unsigned u32x4 __attribute__((ext_vector_type(4)));

#define MTOT 8192
#define CDIM 1024
#define HEADS 8
#define DV 128
#define QKD 128
#define SEQ 2048
#define QSCALE 0.3606737602222409f   // 0.25 * log2(e): softmax scale folded into Q

struct alignas(8) B4 { bf16_t a, b, c, d; };

__device__ inline bf16x8 cvt8(float4 a, float4 b) {
    bf16x8 v = { (bf16_t)a.x, (bf16_t)a.y, (bf16_t)a.z, (bf16_t)a.w,
                 (bf16_t)b.x, (bf16_t)b.y, (bf16_t)b.z, (bf16_t)b.w };
    return v;
}

__device__ inline void gl_lds16(const bf16_t* g, bf16_t* l) {
    __builtin_amdgcn_global_load_lds(
        (const __attribute__((address_space(1))) void*)g,
        (__attribute__((address_space(3))) void*)l, 16, 0, 0);
}

__device__ inline unsigned pk2(float a, float b) {
    union { bf16_t h[2]; unsigned u; } x;
    x.h[0] = (bf16_t)a; x.h[1] = (bf16_t)b;
    return x.u;
}

// ---------------------------------------------------------------------------
__global__ __launch_bounds__(256) void cvt_x(
    const float* __restrict__ src, bf16_t* __restrict__ dst, int n8)
{
    int i = blockIdx.x * blockDim.x + threadIdx.x;
    if (i >= n8) return;
    const float4* s = reinterpret_cast<const float4*>(src) + (size_t)i * 2;
    reinterpret_cast<bf16x8*>(dst)[i] = cvt8(s[0], s[1]);
}

__global__ __launch_bounds__(256) void cvt_w(
    const float* __restrict__ Wq, const float* __restrict__ Wk,
    const float* __restrict__ Wv, bf16_t* __restrict__ Wb)
{
    int i = blockIdx.x * blockDim.x + threadIdx.x;
    const float* src;
    if (i < 16384)       src = Wq + (size_t)i * 8;
    else if (i < 32768)  src = Wk + (size_t)(i - 16384) * 8;
    else                 src = Wv + (size_t)(i - 32768) * 8;
    const float4* s = reinterpret_cast<const float4*>(src);
    reinterpret_cast<bf16x8*>(Wb)[i] = cvt8(s[0], s[1]);
}

// ---------------------------------------------------------------------------
// m97-structure GEMM (R8-proven): bf16 in, 128x128 tile, BK=64, global_load_lds.
// ---------------------------------------------------------------------------
__global__ __launch_bounds__(256) void qkv_gemm3(
    const bf16_t* __restrict__ Xb, const bf16_t* __restrict__ Wb,
    const float* __restrict__ bq, const float* __restrict__ bk,
    const float* __restrict__ bv,
    bf16_t* __restrict__ Qw, bf16_t* __restrict__ Kw, bf16_t* __restrict__ Vt)
{
    __shared__ bf16_t As[128][64];
    __shared__ bf16_t Bs[128][64];

    const int tid = threadIdx.x;
    const int w = tid >> 6, l = tid & 63;
    const int c = l & 15, q = l >> 4;
    const int rw = w & 1, cw = w >> 1;
    const int bx = blockIdx.x;
    const int m0 = blockIdx.y * 128;

    const bf16_t* Arow = Xb + (size_t)(m0 + w * 8 + (l >> 3)) * CDIM + (l & 7) * 8;
    const bf16_t* Brow = Wb + (size_t)(bx * 128 + w * 8 + (l >> 3)) * CDIM + (l & 7) * 8;

    f32x4 acc[16] = {};

    for (int k0 = 0; k0 < CDIM; k0 += 64) {
        __syncthreads();
        #pragma unroll
        for (int i = 0; i < 4; ++i) {
            gl_lds16(Arow + k0 + (size_t)i * 32 * CDIM, &As[i * 32 + w * 8][0]);
            gl_lds16(Brow + k0 + (size_t)i * 32 * CDIM, &Bs[i * 32 + w * 8][0]);
        }
        __syncthreads();
        #pragma unroll
        for (int kk = 0; kk < 2; ++kk) {
            bf16x8 af[4], bfr[4];
            #pragma unroll
            for (int mt = 0; mt < 4; ++mt)
                af[mt] = *(const bf16x8*)&As[rw * 64 + mt * 16 + c][kk * 32 + q * 8];
            #pragma unroll
            for (int nt = 0; nt < 4; ++nt)
                bfr[nt] = *(const bf16x8*)&Bs[cw * 64 + nt * 16 + c][kk * 32 + q * 8];
            #pragma unroll
            for (int mt = 0; mt < 4; ++mt)
                #pragma unroll
                for (int nt = 0; nt < 4; ++nt)
                    acc[mt * 4 + nt] = __builtin_amdgcn_mfma_f32_16x16x32_bf16(
                        af[mt], bfr[nt], acc[mt * 4 + nt], 0, 0, 0);
        }
    }

    #pragma unroll
    for (int mt = 0; mt < 4; ++mt)
        #pragma unroll
        for (int nt = 0; nt < 4; ++nt) {
            const int cl = cw * 64 + nt * 16 + c;
            f32x4 a = acc[mt * 4 + nt];
            const int mg = m0 + rw * 64 + mt * 16 + q * 4;
            if (bx == 0) {
                const float bb = bq[cl];
                #pragma unroll
                for (int r = 0; r < 4; ++r)
                    Qw[(size_t)(mg + r) * QKD + cl] = (bf16_t)((a[r] + bb) * QSCALE);
            } else if (bx == 1) {
                const float bb = bk[cl];
                #pragma unroll
                for (int r = 0; r < 4; ++r)
                    Kw[(size_t)(mg + r) * QKD + cl] = (bf16_t)(a[r] + bb);
            } else {
                const int h = bx - 2;
                const float bb = bv[h * DV + cl];
                const int bidx = mg >> 11, ml = mg & 2047;
                B4 v{ (bf16_t)(a[0] + bb), (bf16_t)(a[1] + bb),
                      (bf16_t)(a[2] + bb), (bf16_t)(a[3] + bb) };
                *(B4*)(Vt + ((size_t)(bidx * HEADS + h) * DV + cl) * SEQ + ml) = v;
            }
        }
}

// ---------------------------------------------------------------------------
// Fallback fp32-input GEMM (R7-proven).
// ---------------------------------------------------------------------------
__global__ __launch_bounds__(256, 2) void qkv_gemm2(
    const float* __restrict__ X,
    const float* __restrict__ Wq, const float* __restrict__ bq,
    const float* __restrict__ Wk, const float* __restrict__ bk,
    const float* __restrict__ Wv, const float* __restrict__ bv,
    bf16_t* __restrict__ Qw, bf16_t* __restrict__ Kw, bf16_t* __restrict__ Vt)
{
    __shared__ alignas(16) bf16_t As[128][72];
    __shared__ alignas(16) bf16_t Bs[128][72];

    const int tid  = threadIdx.x;
    const int lane = tid & 63, wave = tid >> 6;
    const int c = lane & 15, q = lane >> 4;
    const int rw = wave & 1, cw = wave >> 1;
    const int m0 = blockIdx.y * 128;
    const int nt_idx = blockIdx.x;

    const float* W; const float* bias;
    if (nt_idx == 0)      { W = Wq; bias = bq; }
    else if (nt_idx == 1) { W = Wk; bias = bk; }
    else { W = Wv + (size_t)(nt_idx - 2) * DV * CDIM; bias = bv + (nt_idx - 2) * DV; }

    const int srow = tid >> 1, sseg = tid & 1;
    const int swr = (srow >> 3) & 3;
    const float* ax = X + (size_t)(m0 + srow) * CDIM + sseg * 32;
    const float* bxp = W + (size_t)srow * CDIM + sseg * 32;

    f32x4 acc[16] = {};

    for (int k0 = 0; k0 < CDIM; k0 += 64) {
        __syncthreads();
        #pragma unroll
        for (int i = 0; i < 4; ++i) {
            const int ph = (sseg * 4 + i) ^ swr;
            *(bf16x8*)&As[srow][ph * 8] = cvt8(*(const float4*)(ax + k0 + i * 8),
                                               *(const float4*)(ax + k0 + i * 8 + 4));
            *(bf16x8*)&Bs[srow][ph * 8] = cvt8(*(const float4*)(bxp + k0 + i * 8),
                                               *(const float4*)(bxp + k0 + i * 8 + 4));
        }
        __syncthreads();
        #pragma unroll
        for (int kk = 0; kk < 2; ++kk) {
            bf16x8 af[4], bfr[4];
            #pragma unroll
            for (int mt = 0; mt < 4; ++mt) {
                const int row = rw * 64 + mt * 16 + c;
                af[mt] = *(const bf16x8*)&As[row][((kk * 4 + q) ^ ((row >> 3) & 3)) * 8];
            }
            #pragma unroll
            for (int nt = 0; nt < 4; ++nt) {
                const int row = cw * 64 + nt * 16 + c;
                bfr[nt] = *(const bf16x8*)&Bs[row][((kk * 4 + q) ^ ((row >> 3) & 3)) * 8];
            }
            #pragma unroll
            for (int mt = 0; mt < 4; ++mt)
                #pragma unroll
                for (int nt = 0; nt < 4; ++nt)
                    acc[mt * 4 + nt] = __builtin_amdgcn_mfma_f32_16x16x32_bf16(
                        af[mt], bfr[nt], acc[mt * 4 + nt], 0, 0, 0);
        }
    }

    #pragma unroll
    for (int mt = 0; mt < 4; ++mt)
        #pragma unroll
        for (int nt = 0; nt < 4; ++nt) {
            const int col = cw * 64 + nt * 16 + c;
            const float bb = bias[col];
            f32x4 a = acc[mt * 4 + nt];
            const int mg = m0 + rw * 64 + mt * 16 + q * 4;
            if (nt_idx == 0) {
                #pragma unroll
                for (int r = 0; r < 4; ++r)
                    Qw[(size_t)(mg + r) * QKD + col] = (bf16_t)((a[r] + bb) * QSCALE);
            } else if (nt_idx == 1) {
                #pragma unroll
                for (int r = 0; r < 4; ++r)
                    Kw[(size_t)(mg + r) * QKD + col] = (bf16_t)(a[r] + bb);
            } else {
                const int h = nt_idx - 2;
                const int bidx = mg >> 11, ml = mg & 2047;
                B4 v{ (bf16_t)(a[0] + bb), (bf16_t)(a[1] + bb),
                      (bf16_t)(a[2] + bb), (bf16_t)(a[3] + bb) };
                *(B4*)(Vt + ((size_t)(bidx * HEADS + h) * DV + col) * SEQ + ml) = v;
            }
        }
}

// ---------------------------------------------------------------------------
// Flash attention v4: register-resident P (shfl_xor C->A transform),
// double-buffered Vs (ONE barrier/tile), XCD-aware block swizzle.
// 1-D grid 512. Lane owns one q-row (S^T = K.Q^T, 32x32x16 MFMA).
// ---------------------------------------------------------------------------
__global__ __launch_bounds__(256, 2) void attn4(
    const bf16_t* __restrict__ Q, const bf16_t* __restrict__ K,
    const bf16_t* __restrict__ Vt, const float* __restrict__ X,
    const float* __restrict__ gptr, float* __restrict__ out)
{
    __shared__ alignas(16) bf16_t Vs[2][128][72];   // 36.9 KB, dbuf

    const int tid  = threadIdx.x;
    const int lane = tid & 63, wave = tid >> 6;
    const int c5 = lane & 31, q1 = lane >> 5;

    // XCD swizzle: all 16 m-tiles of one (b,h) share id%8
    const int id = blockIdx.x;
    const int t8 = id >> 3;
    const int bh = (t8 >> 4) * 8 + (id & 7);
    const int mtile = t8 & 15;
    const int b = bh >> 3, h = bh & 7;
    const int mbase = mtile * 128 + wave * 32;

    const bf16x8 qf = *(const bf16x8*)(
        Q + (size_t)(b * SEQ + mbase + c5) * QKD + h * 16 + q1 * 8);

    float li = 0.f;
    f32x16 o[4] = {};

    const bf16_t* Vhead = Vt + (size_t)(b * HEADS + h) * DV * SEQ;
    const bf16_t* Kbase = K + (size_t)(b * SEQ) * QKD + h * 16;

    const int sdv = tid >> 1, sseg = tid & 1;
    const int swv = (sdv >> 3) & 7;

    bf16x8 vreg[4], kreg[2];
    {   // prefetch + stage tile 0
        const bf16_t* src = Vhead + (size_t)sdv * SEQ + sseg * 32;
        #pragma unroll
        for (int i = 0; i < 4; ++i) vreg[i] = *(const bf16x8*)(src + i * 8);
        #pragma unroll
        for (int blk = 0; blk < 2; ++blk)
            kreg[blk] = *(const bf16x8*)(Kbase + (size_t)(blk * 32 + c5) * QKD + q1 * 8);
        #pragma unroll
        for (int i = 0; i < 4; ++i)
            *(bf16x8*)&Vs[0][sdv][(((sseg * 4 + i) ^ swv)) * 8] = vreg[i];
    }
    __syncthreads();

    for (int it = 0; it < SEQ / 64; ++it) {
        const int cur = it & 1, nxt = cur ^ 1;
        const bf16x8 k0f = kreg[0], k1f = kreg[1];

        if (it + 1 < SEQ / 64) {   // prefetch next tile into regs
            const int n1 = (it + 1) * 64;
            const bf16_t* src = Vhead + (size_t)sdv * SEQ + n1 + sseg * 32;
            #pragma unroll
            for (int i = 0; i < 4; ++i) vreg[i] = *(const bf16x8*)(src + i * 8);
            #pragma unroll
            for (int blk = 0; blk < 2; ++blk)
                kreg[blk] = *(const bf16x8*)(
                    Kbase + (size_t)(n1 + blk * 32 + c5) * QKD + q1 * 8);
        }

        #pragma unroll
        for (int blk = 0; blk < 2; ++blk) {
            f32x16 z = {};
            f32x16 s = __builtin_amdgcn_mfma_f32_32x32x16_bf16(
                blk ? k1f : k0f, qf, z, 0, 0, 0);

            float pe[16];
            #pragma unroll
            for (int r = 0; r < 16; ++r) {
                const float sv = s[r];
                const float e = __builtin_amdgcn_exp2f(fmaxf(sv, 0.2f * sv));
                pe[r] = e;
                li += e;
            }

            // pack pairs: w0..w3 = regs 0..7 (kt_loc 0), w4..w7 = regs 8..15
            unsigned wd[8];
            #pragma unroll
            for (int i = 0; i < 8; ++i) wd[i] = pk2(pe[2 * i], pe[2 * i + 1]);

            #pragma unroll
            for (int kt = 0; kt < 2; ++kt) {
                const unsigned* wp = wd + kt * 4;
                // keep = my half; send = what partner needs
                const unsigned kA = q1 ? wp[2] : wp[0];
                const unsigned kB = q1 ? wp[3] : wp[1];
                const unsigned sA = q1 ? wp[0] : wp[2];
                const unsigned sB = q1 ? wp[1] : wp[3];
                const unsigned rA = (unsigned)__shfl_xor((int)sA, 32);
                const unsigned rB = (unsigned)__shfl_xor((int)sB, 32);
                u32x4 fw = q1 ? (u32x4){rA, rB, kA, kB}
                              : (u32x4){kA, kB, rA, rB};
                bf16x8 pa;
                __builtin_memcpy(&pa, &fw, 16);

                const int ktg = blk * 2 + kt;
                #pragma unroll
                for (int dvt = 0; dvt < 4; ++dvt) {
                    const int dv = dvt * 32 + c5;
                    const int phB = (ktg * 2 + q1) ^ ((dv >> 3) & 7);
                    const bf16x8 vb = *(const bf16x8*)&Vs[cur][dv][phB * 8];
                    o[dvt] = __builtin_amdgcn_mfma_f32_32x32x16_bf16(pa, vb, o[dvt], 0, 0, 0);
                }
            }
        }

        if (it + 1 < SEQ / 64) {   // stage next tile (waits on prefetch loads)
            #pragma unroll
            for (int i = 0; i < 4; ++i)
                *(bf16x8*)&Vs[nxt][sdv][(((sseg * 4 + i) ^ swv)) * 8] = vreg[i];
        }
        __syncthreads();   // single barrier: Vs[nxt] ready AND Vs[cur] readers done
    }

    li += __shfl_xor(li, 32);
    const float inv = 1.f / li;
    const float g = gptr[0];

    #pragma unroll
    for (int dvt = 0; dvt < 4; ++dvt)
        #pragma unroll
        for (int r = 0; r < 16; ++r) {
            const int row = (r & 3) + 8 * (r >> 2) + 4 * q1;
            const float linv = __shfl(inv, row);
            const size_t idx = (size_t)(b * SEQ + mbase + row) * CDIM
                             + h * DV + dvt * 32 + c5;
            out[idx] = g * (o[dvt][r] * linv) + X[idx];
        }
}

extern "C" void kernel_launch(void* const* d_in, const int* in_sizes, int n_in,
                              void* d_out, int out_size, void* d_ws, size_t ws_size,
                              hipStream_t stream) {
    const float* X  = (const float*)d_in[0];
    const float* Wq = (const float*)d_in[1];
    const float* bq = (const float*)d_in[2];
    const float* Wk = (const float*)d_in[3];
    const float* bk = (const float*)d_in[4];
    const float* Wv = (const float*)d_in[5];
    const float* bv = (const float*)d_in[6];
    const float* g  = (const float*)d_in[7];
    float* out = (float*)d_out;

    dim3 blk(256);
    const size_t big_elems = (size_t)MTOT * CDIM + 1280 * CDIM
                           + (size_t)MTOT * QKD * 2 + (size_t)MTOT * CDIM;
    const size_t big_ws = big_elems * sizeof(bf16_t);   // 40.4 MB

    if (ws_size >= big_ws) {
        bf16_t* Xb = (bf16_t*)d_ws;
        bf16_t* Wb = Xb + (size_t)MTOT * CDIM;
        bf16_t* Qw = Wb + (size_t)1280 * CDIM;
        bf16_t* Kw = Qw + (size_t)MTOT * QKD;
        bf16_t* Vt = Kw + (size_t)MTOT * QKD;

        hipLaunchKernelGGL(cvt_x, dim3(MTOT * CDIM / 8 / 256), blk, 0, stream,
                           X, Xb, MTOT * CDIM / 8);
        hipLaunchKernelGGL(cvt_w, dim3(1280 * CDIM / 8 / 256), blk, 0, stream,
                           Wq, Wk, Wv, Wb);
        hipLaunchKernelGGL(qkv_gemm3, dim3(10, 64), blk, 0, stream,
                           Xb, Wb, bq, bk, bv, Qw, Kw, Vt);
        hipLaunchKernelGGL(attn4, dim3(512), blk, 0, stream,
                           Qw, Kw, Vt, X, g, out);
    } else {
        bf16_t* Qw = (bf16_t*)d_ws;
        bf16_t* Kw = Qw + (size_t)MTOT * QKD;
        bf16_t* Vt = Kw + (size_t)MTOT * QKD;
        hipLaunchKernelGGL(qkv_gemm2, dim3(10, 64), blk, 0, stream,
                           X, Wq, bq, Wk, bk, Wv, bv, Qw, Kw, Vt);
        hipLaunchKernelGGL(attn4, dim3(512), blk, 0, stream,
                           Qw, Kw, Vt, X, g, out);
    }
}